// Round 2
// baseline (866.932 us; speedup 1.0000x reference)
//
#include <hip/hip_runtime.h>

// MoE FFN: top-2 of 8 routed SwiGLU experts + shared expert.
// T=4096 tokens, H=1024, F=2752. fp32 in/out, bf16 MFMA internally.

#define Hdim 1024
#define Fdim 2752
#define Edim 8
#define Tdim 4096

typedef unsigned short u16;
typedef __bf16 bf16x8 __attribute__((ext_vector_type(8)));
typedef float f32x4 __attribute__((ext_vector_type(4)));

#define MFMA16(a, b, c) __builtin_amdgcn_mfma_f32_16x16x32_bf16(a, b, c, 0, 0, 0)

__device__ __forceinline__ u16 f2bf(float f) {  // fp32 -> bf16 bits, RNE
  unsigned u = __float_as_uint(f);
  u += 0x7fffu + ((u >> 16) & 1u);
  return (u16)(u >> 16);
}

// ---------- transpose + convert: src[R][C] fp32 -> dst[C][R] bf16 ----------
__global__ __launch_bounds__(256) void transpose_k(const float* __restrict__ src,
                                                   u16* __restrict__ dst, int R, int C) {
  __shared__ float tile[64][65];
  const size_t zoff = (size_t)blockIdx.z * R * C;
  src += zoff; dst += zoff;
  const int r0 = blockIdx.y * 64, c0 = blockIdx.x * 64;
  const int tx = threadIdx.x & 63, ty = threadIdx.x >> 6;
#pragma unroll
  for (int i = 0; i < 16; i++) {
    int row = ty * 16 + i;
    tile[row][tx] = src[(size_t)(r0 + row) * C + (c0 + tx)];
  }
  __syncthreads();
#pragma unroll
  for (int i = 0; i < 16; i++) {
    int crow = ty * 16 + i;
    dst[(size_t)(c0 + crow) * R + (r0 + tx)] = f2bf(tile[tx][crow]);
  }
}

// ---------- gate: exact fp32 softmax top-2, build gather lists; x -> bf16 ----------
__global__ __launch_bounds__(64) void gate_k(const float* __restrict__ x,
                                             const float* __restrict__ gw,
                                             u16* __restrict__ xbf,
                                             int* __restrict__ counts,
                                             int* __restrict__ tok,
                                             float* __restrict__ wt) {
  const int t = blockIdx.x, lane = threadIdx.x;
  const float* xr = x + (size_t)t * Hdim;
  float acc[Edim];
#pragma unroll
  for (int e = 0; e < Edim; e++) acc[e] = 0.f;
  for (int i = 0; i < Hdim / 64; i++) {
    int idx = i * 64 + lane;
    float xv = xr[idx];
    xbf[(size_t)t * Hdim + idx] = f2bf(xv);
#pragma unroll
    for (int e = 0; e < Edim; e++) acc[e] += xv * gw[e * Hdim + idx];
  }
#pragma unroll
  for (int e = 0; e < Edim; e++)
    for (int o = 32; o > 0; o >>= 1) acc[e] += __shfl_xor(acc[e], o, 64);
  if (lane == 0) {
    float m = acc[0];
    for (int e = 1; e < Edim; e++) m = fmaxf(m, acc[e]);
    float p[Edim], ssum = 0.f;
    for (int e = 0; e < Edim; e++) { p[e] = expf(acc[e] - m); ssum += p[e]; }
    // top-2 on logits (monotone w/ softmax); strict > keeps lowest index on ties (jax top_k)
    int i1 = 0; float l1 = acc[0];
    for (int e = 1; e < Edim; e++) if (acc[e] > l1) { l1 = acc[e]; i1 = e; }
    int i2 = -1; float l2 = -1e30f;
    for (int e = 0; e < Edim; e++) if (e != i1 && acc[e] > l2) { l2 = acc[e]; i2 = e; }
    float s1 = p[i1] / ssum, s2 = p[i2] / ssum;
    float den = s1 + s2 + 1e-20f;
    float w1 = s1 / den, w2 = s2 / den;
    int p1 = atomicAdd(&counts[i1], 1);
    tok[i1 * Tdim + p1] = t; wt[i1 * Tdim + p1] = w1;
    int p2 = atomicAdd(&counts[i2], 1);
    tok[i2 * Tdim + p2] = t; wt[i2 * Tdim + p2] = w2;
  }
}

__global__ void scan_k(const int* __restrict__ counts, int* __restrict__ offs) {
  if (threadIdx.x == 0) {
    int a = 0;
    for (int e = 0; e < Edim; e++) { offs[e] = a; a += counts[e]; }
    offs[Edim] = a;
  }
}

// ---------- GEMM1: s = silu(X@Wg) * (X@Wu), gathered rows, bf16 out ----------
// Block: 128 rows x 64 f-cols (both G and U). 4 waves, each 64x32 of both.
// Staging: each thread copies 2x uint4 (= 2x8 u16) per buffer -> full 32-elem K-slab.
#define LDP 40  // LDS row stride (elems): 80 B, 16B-aligned, 2-way banks (free)
template <bool GATHER>
__global__ __launch_bounds__(256) void gemm1_k(const u16* __restrict__ xbf,
                                               const u16* __restrict__ wg_t,  // [E][F][H] bf16
                                               const u16* __restrict__ wu_t,
                                               const int* __restrict__ tok_list,
                                               const int* __restrict__ counts,
                                               const int* __restrict__ offs,
                                               u16* __restrict__ s_out,
                                               int e_base) {
  const int e = e_base + blockIdx.z;
  const int nrows = GATHER ? counts[e] : Tdim;
  const int m0 = blockIdx.y * 128;
  if (m0 >= nrows) return;
  const int n0 = blockIdx.x * 64;
  const int srow0 = GATHER ? (offs[e] + m0) : m0;

  __shared__ u16 lA[128 * LDP];
  __shared__ u16 lBG[64 * LDP];
  __shared__ u16 lBU[64 * LDP];

  const int tid = threadIdx.x;
  // A staging: 128 rows; thread covers elems half*8+[0,8) and half*8+16+[0,8)
  const int arow = tid >> 1, ahalf = tid & 1;
  int ar = m0 + arow; if (ar > nrows - 1) ar = nrows - 1;
  const int tokA = GATHER ? tok_list[(size_t)e * Tdim + ar] : ar;
  const u16* aSrc = xbf + (size_t)tokA * Hdim + ahalf * 8;
  u16* aDst = lA + arow * LDP + ahalf * 8;
  // B staging: 2 matrices x 64 rows x 2 halves
  const int bsel = tid >> 7, brow = (tid & 127) >> 1, bhalf = tid & 1;
  const u16* bSrc = (bsel ? wu_t : wg_t) + (size_t)e * Fdim * Hdim +
                    (size_t)(n0 + brow) * Hdim + bhalf * 8;
  u16* bDst = (bsel ? lBU : lBG) + brow * LDP + bhalf * 8;

  const int wave = tid >> 6, lane = tid & 63;
  const int wm = (wave & 1) * 64, wn = (wave >> 1) * 32;
  const int lrow = lane & 15, lk = (lane >> 4) * 8;

  f32x4 zero = {0.f, 0.f, 0.f, 0.f};
  f32x4 accG[4][2], accU[4][2];
#pragma unroll
  for (int mt = 0; mt < 4; mt++)
#pragma unroll
    for (int nt = 0; nt < 2; nt++) { accG[mt][nt] = zero; accU[mt][nt] = zero; }

  for (int k0 = 0; k0 < Hdim; k0 += 32) {
    __syncthreads();
    *(uint4*)aDst = *(const uint4*)(aSrc + k0);
    *(uint4*)(aDst + 16) = *(const uint4*)(aSrc + k0 + 16);
    *(uint4*)bDst = *(const uint4*)(bSrc + k0);
    *(uint4*)(bDst + 16) = *(const uint4*)(bSrc + k0 + 16);
    __syncthreads();
    bf16x8 af[4], bg[2], bu[2];
#pragma unroll
    for (int mt = 0; mt < 4; mt++)
      af[mt] = *(const bf16x8*)(lA + (wm + mt * 16 + lrow) * LDP + lk);
#pragma unroll
    for (int nt = 0; nt < 2; nt++) {
      bg[nt] = *(const bf16x8*)(lBG + (wn + nt * 16 + lrow) * LDP + lk);
      bu[nt] = *(const bf16x8*)(lBU + (wn + nt * 16 + lrow) * LDP + lk);
    }
#pragma unroll
    for (int mt = 0; mt < 4; mt++)
#pragma unroll
      for (int nt = 0; nt < 2; nt++) {
        accG[mt][nt] = MFMA16(af[mt], bg[nt], accG[mt][nt]);
        accU[mt][nt] = MFMA16(af[mt], bu[nt], accU[mt][nt]);
      }
  }
  // epilogue: silu(g)*u -> bf16
#pragma unroll
  for (int mt = 0; mt < 4; mt++)
#pragma unroll
    for (int nt = 0; nt < 2; nt++)
#pragma unroll
      for (int r = 0; r < 4; r++) {
        int row = wm + mt * 16 + (lane >> 4) * 4 + r;
        if (m0 + row < nrows) {
          float g = accG[mt][nt][r], u = accU[mt][nt][r];
          float sv = g * (1.0f / (1.0f + __expf(-g))) * u;
          s_out[(size_t)(srow0 + row) * Fdim + (n0 + wn + nt * 16 + (lane & 15))] = f2bf(sv);
        }
      }
}

// ---------- GEMM2: Y = s @ Wd; routed: atomicAdd(out, w*Y); shared: store ----------
template <bool GATHER>
__global__ __launch_bounds__(256) void gemm2_k(const u16* __restrict__ s_in,
                                               const u16* __restrict__ wd_t,  // [E][H][F] bf16
                                               const int* __restrict__ tok_list,
                                               const int* __restrict__ counts,
                                               const int* __restrict__ offs,
                                               const float* __restrict__ wt_list,
                                               float* __restrict__ out,
                                               int e_base) {
  const int e = e_base + blockIdx.z;
  const int nrows = GATHER ? counts[e] : Tdim;
  const int m0 = blockIdx.y * 128;
  if (m0 >= nrows) return;
  const int n0 = blockIdx.x * 128;

  __shared__ u16 lA[128 * LDP];
  __shared__ u16 lB[128 * LDP];

  const int tid = threadIdx.x;
  const int arow = tid >> 1, ahalf = tid & 1;
  int ar = m0 + arow; if (ar > nrows - 1) ar = nrows - 1;
  const size_t asrow = GATHER ? (size_t)(offs[e] + ar) : (size_t)ar;
  const u16* aSrc = s_in + asrow * Fdim + ahalf * 8;
  u16* aDst = lA + arow * LDP + ahalf * 8;
  const u16* bSrc = wd_t + (size_t)e * Hdim * Fdim + (size_t)(n0 + arow) * Fdim + ahalf * 8;
  u16* bDst = lB + arow * LDP + ahalf * 8;

  const int wave = tid >> 6, lane = tid & 63;
  const int wm = (wave & 1) * 64, wn = (wave >> 1) * 64;
  const int lrow = lane & 15, lk = (lane >> 4) * 8;

  f32x4 zero = {0.f, 0.f, 0.f, 0.f};
  f32x4 acc[4][4];
#pragma unroll
  for (int mt = 0; mt < 4; mt++)
#pragma unroll
    for (int nt = 0; nt < 4; nt++) acc[mt][nt] = zero;

  for (int k0 = 0; k0 < Fdim; k0 += 32) {
    __syncthreads();
    *(uint4*)aDst = *(const uint4*)(aSrc + k0);
    *(uint4*)(aDst + 16) = *(const uint4*)(aSrc + k0 + 16);
    *(uint4*)bDst = *(const uint4*)(bSrc + k0);
    *(uint4*)(bDst + 16) = *(const uint4*)(bSrc + k0 + 16);
    __syncthreads();
    bf16x8 af[4], bf[4];
#pragma unroll
    for (int mt = 0; mt < 4; mt++)
      af[mt] = *(const bf16x8*)(lA + (wm + mt * 16 + lrow) * LDP + lk);
#pragma unroll
    for (int nt = 0; nt < 4; nt++)
      bf[nt] = *(const bf16x8*)(lB + (wn + nt * 16 + lrow) * LDP + lk);
#pragma unroll
    for (int mt = 0; mt < 4; mt++)
#pragma unroll
      for (int nt = 0; nt < 4; nt++)
        acc[mt][nt] = MFMA16(af[mt], bf[nt], acc[mt][nt]);
  }
#pragma unroll
  for (int mt = 0; mt < 4; mt++)
#pragma unroll
    for (int nt = 0; nt < 4; nt++)
#pragma unroll
      for (int r = 0; r < 4; r++) {
        int row = wm + mt * 16 + (lane >> 4) * 4 + r;
        if (m0 + row < nrows) {
          int col = n0 + wn + nt * 16 + (lane & 15);
          float v = acc[mt][nt][r];
          if (GATHER) {
            int t = tok_list[(size_t)e * Tdim + m0 + row];
            float w = wt_list[(size_t)e * Tdim + m0 + row];
            atomicAdd(out + (size_t)t * Hdim + col, v * w);
          } else {
            out[(size_t)(m0 + row) * Hdim + col] = v;
          }
        }
      }
}

// ---------------- launch ----------------
extern "C" void kernel_launch(void* const* d_in, const int* in_sizes, int n_in,
                              void* d_out, int out_size, void* d_ws, size_t ws_size,
                              hipStream_t stream) {
  const float* x      = (const float*)d_in[0];
  const float* gate_w = (const float*)d_in[1];
  const float* wg     = (const float*)d_in[2];
  const float* wu     = (const float*)d_in[3];
  const float* wd     = (const float*)d_in[4];
  const float* sg     = (const float*)d_in[5];
  const float* su     = (const float*)d_in[6];
  const float* sd     = (const float*)d_in[7];
  float* out = (float*)d_out;
  char* ws = (char*)d_ws;

  // common small buffers
  constexpr size_t O_COUNTS = 0;     // 64 B
  constexpr size_t O_ZOFF   = 64;    // 64 B of zeros (phased-mode "offs")
  constexpr size_t O_OFFS   = 128;   // 64 B
  constexpr size_t O_TOK    = 256;
  constexpr size_t O_WT     = O_TOK + sizeof(int) * (size_t)Edim * Tdim;
  constexpr size_t O_XBF    = O_WT + sizeof(float) * (size_t)Edim * Tdim;
  constexpr size_t O_AFTER  = O_XBF + 2ull * Tdim * Hdim;

  constexpr size_t SZ_EHF = 2ull * Hdim * Fdim;           // one expert matrix, bf16
  // batched layout
  constexpr size_t B_WGT = O_AFTER;
  constexpr size_t B_WUT = B_WGT + SZ_EHF * Edim;
  constexpr size_t B_WDT = B_WUT + SZ_EHF * Edim;
  constexpr size_t B_SGT = B_WDT + SZ_EHF * Edim;
  constexpr size_t B_SUT = B_SGT + SZ_EHF;
  constexpr size_t B_SDT = B_SUT + SZ_EHF;
  constexpr size_t B_SRT = B_SDT + SZ_EHF;                // routed s: [2T][F]
  constexpr size_t B_SSH = B_SRT + 2ull * 2 * Tdim * Fdim;
  constexpr size_t B_END = B_SSH + 2ull * Tdim * Fdim;    // ~218 MiB

  // phased layout (per-expert reuse)
  constexpr size_t P_A = O_AFTER;
  constexpr size_t P_B = P_A + SZ_EHF;
  constexpr size_t P_D = P_B + SZ_EHF;
  constexpr size_t P_S = P_D + SZ_EHF;                    // s: [T][F]

  int*   counts = (int*)(ws + O_COUNTS);
  int*   zoff   = (int*)(ws + O_ZOFF);
  int*   offs   = (int*)(ws + O_OFFS);
  int*   tok    = (int*)(ws + O_TOK);
  float* wt     = (float*)(ws + O_WT);
  u16*   xbf    = (u16*)(ws + O_XBF);

  hipMemsetAsync(ws, 0, 256, stream);  // zero counts + zoff (+offs, rewritten by scan)
  gate_k<<<Tdim, 64, 0, stream>>>(x, gate_w, xbf, counts, tok, wt);
  scan_k<<<1, 64, 0, stream>>>(counts, offs);

  if (ws_size >= B_END) {
    // ---------------- batched path ----------------
    u16* wg_t = (u16*)(ws + B_WGT);
    u16* wu_t = (u16*)(ws + B_WUT);
    u16* wd_t = (u16*)(ws + B_WDT);
    u16* sg_t = (u16*)(ws + B_SGT);
    u16* su_t = (u16*)(ws + B_SUT);
    u16* sd_t = (u16*)(ws + B_SDT);
    u16* s_rt = (u16*)(ws + B_SRT);
    u16* s_sh = (u16*)(ws + B_SSH);

    transpose_k<<<dim3(Fdim / 64, Hdim / 64, Edim), 256, 0, stream>>>(wg, wg_t, Hdim, Fdim);
    transpose_k<<<dim3(Fdim / 64, Hdim / 64, Edim), 256, 0, stream>>>(wu, wu_t, Hdim, Fdim);
    transpose_k<<<dim3(Hdim / 64, Fdim / 64, Edim), 256, 0, stream>>>(wd, wd_t, Fdim, Hdim);
    transpose_k<<<dim3(Fdim / 64, Hdim / 64, 1), 256, 0, stream>>>(sg, sg_t, Hdim, Fdim);
    transpose_k<<<dim3(Fdim / 64, Hdim / 64, 1), 256, 0, stream>>>(su, su_t, Hdim, Fdim);
    transpose_k<<<dim3(Hdim / 64, Fdim / 64, 1), 256, 0, stream>>>(sd, sd_t, Fdim, Hdim);

    gemm1_k<false><<<dim3(Fdim / 64, Tdim / 128, 1), 256, 0, stream>>>(
        xbf, sg_t, su_t, tok, counts, offs, s_sh, 0);
    gemm1_k<true><<<dim3(Fdim / 64, Tdim / 128, Edim), 256, 0, stream>>>(
        xbf, wg_t, wu_t, tok, counts, offs, s_rt, 0);

    gemm2_k<false><<<dim3(Hdim / 128, Tdim / 128, 1), 256, 0, stream>>>(
        s_sh, sd_t, tok, counts, offs, wt, out, 0);
    gemm2_k<true><<<dim3(Hdim / 128, Tdim / 128, Edim), 256, 0, stream>>>(
        s_rt, wd_t, tok, counts, offs, wt, out, 0);
  } else {
    // ---------------- phased path (per-expert buffer reuse, ~46 MiB) ----------------
    u16* A = (u16*)(ws + P_A);
    u16* Bb = (u16*)(ws + P_B);
    u16* D = (u16*)(ws + P_D);
    u16* S = (u16*)(ws + P_S);

    // shared expert
    transpose_k<<<dim3(Fdim / 64, Hdim / 64, 1), 256, 0, stream>>>(sg, A, Hdim, Fdim);
    transpose_k<<<dim3(Fdim / 64, Hdim / 64, 1), 256, 0, stream>>>(su, Bb, Hdim, Fdim);
    transpose_k<<<dim3(Hdim / 64, Fdim / 64, 1), 256, 0, stream>>>(sd, D, Fdim, Hdim);
    gemm1_k<false><<<dim3(Fdim / 64, Tdim / 128, 1), 256, 0, stream>>>(
        xbf, A, Bb, tok, counts, offs, S, 0);
    gemm2_k<false><<<dim3(Hdim / 128, Tdim / 128, 1), 256, 0, stream>>>(
        S, D, tok, counts, offs, wt, out, 0);

    // routed experts, one at a time; zoff (all zeros) makes S per-expert-local.
    for (int e = 0; e < Edim; e++) {
      const size_t weoff = (size_t)e * Hdim * Fdim;
      transpose_k<<<dim3(Fdim / 64, Hdim / 64, 1), 256, 0, stream>>>(wg + weoff, A, Hdim, Fdim);
      transpose_k<<<dim3(Fdim / 64, Hdim / 64, 1), 256, 0, stream>>>(wu + weoff, Bb, Hdim, Fdim);
      transpose_k<<<dim3(Hdim / 64, Fdim / 64, 1), 256, 0, stream>>>(wd + weoff, D, Fdim, Hdim);
      // kernel reads counts[e]/tok[e*T..] via e = e_base + 0; S indexed from 0 via zoff
      gemm1_k<true><<<dim3(Fdim / 64, Tdim / 128, 1), 256, 0, stream>>>(
          xbf, A - weoff, Bb - weoff, tok, counts, zoff, S, e);
      gemm2_k<true><<<dim3(Hdim / 128, Tdim / 128, 1), 256, 0, stream>>>(
          S, D - weoff, tok, counts, zoff, wt, out, e);
    }
  }

  (void)in_sizes; (void)n_in; (void)out_size; (void)ws_size;
}